// Round 7
// baseline (176.414 us; speedup 1.0000x reference)
//
#include <hip/hip_runtime.h>
#include <hip/hip_bf16.h>

// LOIMLoss on MI355X (gfx950) — R19: barrier-free per-wave GEMM streams.
// R18 NEUTRAL (64.3us): deferred-exp didn't help — exp already hidden.
// R14 accounting: period 5511 cyc/chunk; per-SIMD MFMA 621 + VALU ~1700 +
// LDS ~1800/CU => ~40-45% unexplained stall. Suspect: per-chunk s_barrier
// convoy (4 waves x 2 blocks in lockstep = worst case for 2-wave TLP; m114
// overlap needs phase-drifted waves). Barriers exist only for shared staging.
// R19: each wave stages its OWN 16-class chunk (8 KB) into a PRIVATE 16 KB
// LDS double-buffer via 8 gll16; sync = counted per-wave vmcnt ONLY (steady
// vmcnt(8)); ZERO barriers in the loop. 4x L2 traffic (~1.9 TB/s/XCD, under
// limit), HBM unchanged. Read pattern/swizzle byte-identical to R14 per
// 16-class group (src unit = lo ^ 8*(g&3) ^ 4*hi == w^(4*(cc&7))).
// afrag drained with explicit vmcnt(0) so gll16 counting is exact.
//
// Output model (R11, absmax 0.0): d_out f32[out]; [0]=loss, [1..524289)=inputs
// copy, [524289..)=label bf16-RNE upcast. d_in[0..2] f32.

#define NFEAT 256
#define NROIS 2048
#define NPIDS 5554
#define NCLS 55554            // NPIDS + 50000
#define NCHUNKS 3473          // ceil(NCLS/16)
#define NCLSP 55584           // padded table rows (>= 3473*16=55568), zeroed
#define S2F 43.280851226668906f   // 30 * log2(e)
#define LN2F 0.6931471805599453f
#define LOFF 524289

typedef float f32x4 __attribute__((ext_vector_type(4)));
typedef short bf16x8 __attribute__((ext_vector_type(8)));
typedef unsigned short u16x8 __attribute__((ext_vector_type(8)));

#if __has_builtin(__builtin_amdgcn_exp2f)
#define EXP2(x) __builtin_amdgcn_exp2f(x)
#else
#define EXP2(x) exp2f(x)
#endif

__device__ __forceinline__ short bfb(float x) {
    return __builtin_bit_cast(short, __float2bfloat16(x));   // RNE
}

// 16B global->LDS direct (dest = wave-uniform base + lane*16, src per-lane).
__device__ __forceinline__ void gll16(const void* g, void* l) {
    __builtin_amdgcn_global_load_lds(
        (const __attribute__((address_space(1))) void*)g,
        (__attribute__((address_space(3))) void*)l, 16, 0, 0);
}

// ---- kernel A: fused prep + table cvt (+zero pad) + inputs copy + ab cvt ----
__global__ __launch_bounds__(256) void preprocess(
        const float* __restrict__ inputs, const float* __restrict__ lut,
        const float* __restrict__ cq, const int* __restrict__ cand0,
        const int* __restrict__ cand1, unsigned short* __restrict__ tb,
        unsigned short* __restrict__ ab, int* __restrict__ lab,
        float* __restrict__ S, float* __restrict__ f, const int useTB) {
    const int tid = threadIdx.x;
    const int bx = blockIdx.x;

    if (bx == 0) {
        __shared__ int smode;
        __shared__ const int* sT;
        if (tid == 0) {
            const int* T = cand0;
            const unsigned u0 = (unsigned)cand0[0];
            const float f0 = __builtin_bit_cast(float, cand0[0]);
            const bool oki = (u0 >= 1u && u0 <= 6000u);
            const bool okf = (f0 >= 1.0f && f0 <= 6000.0f);
            if (!oki && !okf) T = cand1;
            int mode = 0;                      // 0=int32, 1=int64(LE), 2=f32
            const unsigned tu0 = (unsigned)T[0];
            const float tf0 = __builtin_bit_cast(float, T[0]);
            if (tu0 >= 1u && tu0 <= 6000u) mode = ((T[1] | T[3] | T[5] | T[7]) == 0) ? 1 : 0;
            else if (tf0 >= 1.0f && tf0 <= 6000.0f) mode = 2;
            smode = mode; sT = T;
        }
        __syncthreads();
        const int mode = smode;
        const int* T = sT;
        for (int j = tid; j < NROIS; j += 256) {
            int tv;
            if (mode == 1)      tv = T[2 * j];
            else if (mode == 2) tv = (int)__builtin_bit_cast(float, T[j]);
            else                tv = T[j];
            const int lv = tv - 1;
            lab[j] = lv;
            f[LOFF + j] = __bfloat162float(__float2bfloat16((float)lv));
        }
        for (int j = tid; j < NROIS + 8; j += 256) S[j] = 0.0f;  // S, loss, cnt
    }

    if (bx < 512) {
        const int i = bx * 256 + tid;                 // 131072 float4 units
        const float4 v = *reinterpret_cast<const float4*>(inputs + (size_t)i * 4);
        float* o = f + 1 + (size_t)i * 4;             // f+1 unaligned: scalar stores
        o[0] = v.x; o[1] = v.y; o[2] = v.z; o[3] = v.w;
        if (useTB) {
            ushort4 u;
            u.x = (unsigned short)bfb(v.x); u.y = (unsigned short)bfb(v.y);
            u.z = (unsigned short)bfb(v.z); u.w = (unsigned short)bfb(v.w);
            *reinterpret_cast<ushort4*>(ab + (size_t)i * 4) = u;
        }
    }

    if (useTB) {
        const size_t LUTN = (size_t)NPIDS * NFEAT;    // divisible by 8
        const size_t TOT  = (size_t)NCLS * NFEAT;     // divisible by 8
        const size_t TOTP = (size_t)NCLSP * NFEAT;
        const size_t stride = (size_t)gridDim.x * 256 * 8;
        for (size_t e = ((size_t)bx * 256 + tid) * 8; e < TOTP; e += stride) {
            u16x8 o = {0, 0, 0, 0, 0, 0, 0, 0};
            if (e < TOT) {
                const float* sp = (e < LUTN) ? (lut + e) : (cq + (e - LUTN));
                const float4 a = *reinterpret_cast<const float4*>(sp);
                const float4 b = *reinterpret_cast<const float4*>(sp + 4);
                o[0] = (unsigned short)bfb(a.x); o[1] = (unsigned short)bfb(a.y);
                o[2] = (unsigned short)bfb(a.z); o[3] = (unsigned short)bfb(a.w);
                o[4] = (unsigned short)bfb(b.x); o[5] = (unsigned short)bfb(b.y);
                o[6] = (unsigned short)bfb(b.z); o[7] = (unsigned short)bfb(b.w);
            }
            *reinterpret_cast<u16x8*>(tb + e) = o;
        }
    }
}

// ---- kernel B: main GEMM v8 -------------------------------------------------
// grid 512 = 8 row-groups x 64 class-slices (bx%8 = cs%8 -> XCD-local B slice
// fits L2). 4 waves x 64 rows (R14-proven ratio); A resident (128 regs).
// TB path: PER-WAVE independent streams. Wave stages its own 16-class chunk
// (8 KB) into private LDS dbuf (wave*16KB; buf = i&1) with 8 gll16/chunk;
// sync = "s_waitcnt vmcnt(8)" (chunk i+1's 8 loads stay in flight), vmcnt(0)
// on last. NO s_barrier in the loop — waves drift -> per-SIMD phase diversity.
// Staging: load g stages classes 2g,2g+1; lane l (hi=l>>5, lo=l&31) fetches
// global unit lo^(8*(g&3))^(4*hi) of class c16+2g+hi -> LDS slot (2g+hi)*32+lo
// holds unit w^(4*(cc&7)) == R14 layout. Read: slot li*32+((q+4kc)^4*(li&7)).
template <bool TB>
__global__ __launch_bounds__(256, 2) void main_gemm8(const float* __restrict__ inputs,
                                                     const unsigned short* __restrict__ tb,
                                                     const unsigned short* __restrict__ ab,
                                                     const float* __restrict__ lut,
                                                     const float* __restrict__ cq,
                                                     float* __restrict__ S) {
    __shared__ char lds[65536];                   // 4 waves x 16 KB (TB path)
    const int tid = threadIdx.x;
    const int lane = tid & 63;
    const int wave = tid >> 6;
    const int cs = blockIdx.x & 63;
    const int rg = blockIdx.x >> 6;
    const int rowbase = rg * 256 + wave * 64;
    const int li = lane & 15;
    const int q = lane >> 4;
    const int xorli = 4 * (li & 7);
    char* const lbase = &lds[0];

    float sums[4][4] = {{0.f,0.f,0.f,0.f},{0.f,0.f,0.f,0.f},
                        {0.f,0.f,0.f,0.f},{0.f,0.f,0.f,0.f}};

    if constexpr (TB) {
        // A fragments: lane holds A[m=li][k=q*8+kc*32..+7] for 4 row-subtiles
        bf16x8 afrag[4][8];
        #pragma unroll
        for (int s = 0; s < 4; s++) {
            const unsigned short* rp = ab + (size_t)(rowbase + s * 16 + li) * NFEAT + q * 8;
            #pragma unroll
            for (int kc = 0; kc < 8; kc++)
                afrag[s][kc] = *reinterpret_cast<const bf16x8*>(rp + kc * 32);
        }
        // drain afrag loads so gll16 vmcnt counting below is exact
        asm volatile("s_waitcnt vmcnt(0)" ::: "memory");

        const int hi = lane >> 5;                 // staging lane split
        const int lo = lane & 31;
        const int u0 = lo ^ (4 * hi);             // pre-swizzled unit base
        char* const wb = lbase + wave * 16384;    // wave-private 16 KB

        const int cA = (cs * NCHUNKS) >> 6;
        const int cB = ((cs + 1) * NCHUNKS) >> 6;
        const int NB = cB - cA;

        // STAGE chunk c (16 classes) into buffer buf: 8 gll16, 1 KB each
        #define STAGE(c16, buf)                                                     \
            {                                                                        \
                _Pragma("unroll")                                                    \
                for (int g = 0; g < 8; g++) {                                        \
                    const unsigned short* src = tb +                                 \
                        (size_t)((c16) * 16 + 2 * g + hi) * NFEAT +                  \
                        (u0 ^ (8 * (g & 3))) * 8;                                    \
                    gll16(src, wb + (buf) * 8192 + g * 1024);                        \
                }                                                                    \
            }

        STAGE(cA, 0);                             // prologue: chunk 0
        for (int i = 0; i < NB; ++i) {
            if (i + 1 < NB) {
                STAGE(cA + i + 1, (i + 1) & 1);   // 16 outstanding
                asm volatile("s_waitcnt vmcnt(8)" ::: "memory");   // chunk i landed
            } else {
                asm volatile("s_waitcnt vmcnt(0)" ::: "memory");
            }
            char* const cbuf = wb + (i & 1) * 8192;
            bf16x8 bfr[8];
            #pragma unroll
            for (int kc = 0; kc < 8; kc++) {
                const int slot = li * 32 + ((q + 4 * kc) ^ xorli);
                bfr[kc] = *reinterpret_cast<const bf16x8*>(cbuf + slot * 16);
            }
            f32x4 acc[4] = {{0.f,0.f,0.f,0.f},{0.f,0.f,0.f,0.f},
                            {0.f,0.f,0.f,0.f},{0.f,0.f,0.f,0.f}};
            __builtin_amdgcn_s_setprio(1);
            #pragma unroll
            for (int kc = 0; kc < 8; kc++) {
                acc[0] = __builtin_amdgcn_mfma_f32_16x16x32_bf16(afrag[0][kc], bfr[kc], acc[0], 0, 0, 0);
                acc[1] = __builtin_amdgcn_mfma_f32_16x16x32_bf16(afrag[1][kc], bfr[kc], acc[1], 0, 0, 0);
                acc[2] = __builtin_amdgcn_mfma_f32_16x16x32_bf16(afrag[2][kc], bfr[kc], acc[2], 0, 0, 0);
                acc[3] = __builtin_amdgcn_mfma_f32_16x16x32_bf16(afrag[3][kc], bfr[kc], acc[3], 0, 0, 0);
            }
            __builtin_amdgcn_s_setprio(0);
            // padded tb rows are zero -> exp(-30) ~ 1e-13: no mask needed
            #pragma unroll
            for (int s = 0; s < 4; s++)
                #pragma unroll
                for (int r = 0; r < 4; r++)
                    sums[s][r] += EXP2(S2F * acc[s][r] - S2F);
        }
        #undef STAGE
    } else {
        // fallback (no ws table): R14 reg-staged double-buffer loop (proven).
        bf16x8 afrag[4][8];
        #pragma unroll
        for (int s = 0; s < 4; s++) {
            const float* rp = inputs + (size_t)(rowbase + s * 16 + li) * NFEAT + q * 8;
            #pragma unroll
            for (int kc = 0; kc < 8; kc++) {
                const float4 x0 = *reinterpret_cast<const float4*>(rp + kc * 32);
                const float4 x1 = *reinterpret_cast<const float4*>(rp + kc * 32 + 4);
                bf16x8 a;
                a[0] = bfb(x0.x); a[1] = bfb(x0.y); a[2] = bfb(x0.z); a[3] = bfb(x0.w);
                a[4] = bfb(x1.x); a[5] = bfb(x1.y); a[6] = bfb(x1.z); a[7] = bfb(x1.w);
                afrag[s][kc] = a;
            }
        }
        short* fb = (short*)lbase;
        const int s0 = tid, s1 = tid + 256;
        const int cc0 = s0 >> 5, cc1 = s1 >> 5;
        const int uo0 = ((s0 & 31) ^ (4 * (cc0 & 7))) * 8;
        const int uo1 = ((s1 & 31) ^ (4 * (cc1 & 7))) * 8;
        const int cA = (cs * NCHUNKS) >> 6;
        const int cB = ((cs + 1) * NCHUNKS) >> 6;
        {
            int n0 = cA * 16 + cc0; n0 = n0 < (NCLS - 1) ? n0 : (NCLS - 1);
            int n1 = cA * 16 + cc1; n1 = n1 < (NCLS - 1) ? n1 : (NCLS - 1);
            const float* r0 = ((n0 < NPIDS) ? lut + (size_t)n0 * NFEAT
                                            : cq + (size_t)(n0 - NPIDS) * NFEAT) + uo0;
            const float* r1 = ((n1 < NPIDS) ? lut + (size_t)n1 * NFEAT
                                            : cq + (size_t)(n1 - NPIDS) * NFEAT) + uo1;
            const float4 a0 = *reinterpret_cast<const float4*>(r0);
            const float4 a1 = *reinterpret_cast<const float4*>(r0 + 4);
            const float4 b0 = *reinterpret_cast<const float4*>(r1);
            const float4 b1 = *reinterpret_cast<const float4*>(r1 + 4);
            bf16x8 v0, v1;
            v0[0]=bfb(a0.x); v0[1]=bfb(a0.y); v0[2]=bfb(a0.z); v0[3]=bfb(a0.w);
            v0[4]=bfb(a1.x); v0[5]=bfb(a1.y); v0[6]=bfb(a1.z); v0[7]=bfb(a1.w);
            v1[0]=bfb(b0.x); v1[1]=bfb(b0.y); v1[2]=bfb(b0.z); v1[3]=bfb(b0.w);
            v1[4]=bfb(b1.x); v1[5]=bfb(b1.y); v1[6]=bfb(b1.z); v1[7]=bfb(b1.w);
            *reinterpret_cast<bf16x8*>(&fb[s0 * 8]) = v0;
            *reinterpret_cast<bf16x8*>(&fb[s1 * 8]) = v1;
        }
        __syncthreads();
        int cur = 0;
        for (int ci = cA; ci < cB; ++ci) {
            const bool pf = (ci + 1 < cB);
            float4 f0a, f0b, f1a, f1b;
            if (pf) {
                int n0 = (ci + 1) * 16 + cc0; n0 = n0 < (NCLS - 1) ? n0 : (NCLS - 1);
                int n1 = (ci + 1) * 16 + cc1; n1 = n1 < (NCLS - 1) ? n1 : (NCLS - 1);
                const float* r0 = ((n0 < NPIDS) ? lut + (size_t)n0 * NFEAT
                                                : cq + (size_t)(n0 - NPIDS) * NFEAT) + uo0;
                const float* r1 = ((n1 < NPIDS) ? lut + (size_t)n1 * NFEAT
                                                : cq + (size_t)(n1 - NPIDS) * NFEAT) + uo1;
                f0a = *reinterpret_cast<const float4*>(r0);
                f0b = *reinterpret_cast<const float4*>(r0 + 4);
                f1a = *reinterpret_cast<const float4*>(r1);
                f1b = *reinterpret_cast<const float4*>(r1 + 4);
            }
            f32x4 acc[4] = {{0.f,0.f,0.f,0.f},{0.f,0.f,0.f,0.f},
                            {0.f,0.f,0.f,0.f},{0.f,0.f,0.f,0.f}};
            #pragma unroll
            for (int kc = 0; kc < 8; kc++) {
                const int slot = li * 32 + ((q + 4 * kc) ^ xorli);
                const bf16x8 b = *reinterpret_cast<const bf16x8*>(&fb[cur * 4096 + slot * 8]);
                acc[0] = __builtin_amdgcn_mfma_f32_16x16x32_bf16(afrag[0][kc], b, acc[0], 0, 0, 0);
                acc[1] = __builtin_amdgcn_mfma_f32_16x16x32_bf16(afrag[1][kc], b, acc[1], 0, 0, 0);
                acc[2] = __builtin_amdgcn_mfma_f32_16x16x32_bf16(afrag[2][kc], b, acc[2], 0, 0, 0);
                acc[3] = __builtin_amdgcn_mfma_f32_16x16x32_bf16(afrag[3][kc], b, acc[3], 0, 0, 0);
            }
            const float valid = ((ci * 16 + li) < NCLS) ? 1.0f : 0.0f;
            #pragma unroll
            for (int s = 0; s < 4; s++)
                #pragma unroll
                for (int r = 0; r < 4; r++)
                    sums[s][r] += valid * EXP2(S2F * (acc[s][r] - 1.0f));
            if (pf) {
                bf16x8 p0, p1;
                p0[0]=bfb(f0a.x); p0[1]=bfb(f0a.y); p0[2]=bfb(f0a.z); p0[3]=bfb(f0a.w);
                p0[4]=bfb(f0b.x); p0[5]=bfb(f0b.y); p0[6]=bfb(f0b.z); p0[7]=bfb(f0b.w);
                p1[0]=bfb(f1a.x); p1[1]=bfb(f1a.y); p1[2]=bfb(f1a.z); p1[3]=bfb(f1a.w);
                p1[4]=bfb(f1b.x); p1[5]=bfb(f1b.y); p1[6]=bfb(f1b.z); p1[7]=bfb(f1b.w);
                *reinterpret_cast<bf16x8*>(&fb[(cur ^ 1) * 4096 + s0 * 8]) = p0;
                *reinterpret_cast<bf16x8*>(&fb[(cur ^ 1) * 4096 + s1 * 8]) = p1;
            }
            __syncthreads();
            cur ^= 1;
        }
    }

    // reduce over the 16 class-lanes, atomically add per-row sum-exp
    #pragma unroll
    for (int s = 0; s < 4; s++)
        #pragma unroll
        for (int r = 0; r < 4; r++) {
            float v = sums[s][r];
            v += __shfl_xor(v, 1); v += __shfl_xor(v, 2);
            v += __shfl_xor(v, 4); v += __shfl_xor(v, 8);
            sums[s][r] = v;
        }
    if (li == 0) {
        #pragma unroll
        for (int s = 0; s < 4; s++)
            #pragma unroll
            for (int r = 0; r < 4; r++)
                atomicAdd(&S[rowbase + s * 16 + q * 4 + r], sums[s][r]);
    }
}

// ---- kernel C: exact f32 label dot + focal; last block writes loss ---------
__global__ __launch_bounds__(256) void focal_final(const float* __restrict__ inputs,
                                                   const float* __restrict__ lut,
                                                   const int* __restrict__ lab,
                                                   const float* __restrict__ S,
                                                   float* __restrict__ loss_acc,
                                                   unsigned int* __restrict__ cnt,
                                                   float* __restrict__ f) {
    const int wave = threadIdx.x >> 6;
    const int lane = threadIdx.x & 63;
    const int row = blockIdx.x * 4 + wave;
    const int label = lab[row];
    const bool valid = (label >= 0 && label < NPIDS);
    const int lr = valid ? label : 0;
    const float4 a = *reinterpret_cast<const float4*>(inputs + (size_t)row * NFEAT + lane * 4);
    const float4 b = *reinterpret_cast<const float4*>(lut + (size_t)lr * NFEAT + lane * 4);
    float v = a.x * b.x + a.y * b.y + a.z * b.z + a.w * b.w;
    #pragma unroll
    for (int m = 1; m < 64; m <<= 1) v += __shfl_xor(v, m);

    __shared__ float red[4];
    if (lane == 0) {
        float fo = 0.0f;
        if (valid) {
            const float l2 = v * S2F;
            const float lse2 = S2F + log2f(S[row]);
            float ce = fmaxf((lse2 - l2) * LN2F, 0.0f);
            const float pt = EXP2(l2 - lse2);
            const float om = 1.0f - pt;
            fo = om * om * ce;
        }
        red[wave] = fo;
    }
    __syncthreads();
    if (threadIdx.x == 0) {
        atomicAdd(loss_acc, red[0] + red[1] + red[2] + red[3]);
        __threadfence();
        const unsigned done = atomicAdd(cnt, 1u) + 1u;
        if (done == gridDim.x) {                       // last block: write loss
            const float tot = atomicAdd(loss_acc, 0.0f);  // coherent read
            f[0] = tot * (1.0f / NROIS);
        }
    }
}

extern "C" void kernel_launch(void* const* d_in, const int* in_sizes, int n_in,
                              void* d_out, int out_size, void* d_ws, size_t ws_size,
                              hipStream_t stream) {
    const float* inputs = (const float*)d_in[0];
    const float* lut    = (const float*)d_in[1];
    const float* cq     = (const float*)d_in[2];
    const int*   cand0  = (const int*)d_in[3];     // targets
    const int*   cand1  = (const int*)((n_in > 4) ? d_in[4] : d_in[3]);
    float* f = (float*)d_out;

    const size_t TBB = (size_t)NCLSP * NFEAT * 2;  // 28.46 MB padded bf16 table
    const size_t ABB = (size_t)NROIS * NFEAT * 2;  // 1 MB bf16 A
    char* ws = (char*)d_ws;
    const bool useTB = ws_size >= TBB + ABB + 32768;

    unsigned short* tb = useTB ? (unsigned short*)ws : nullptr;
    unsigned short* ab = useTB ? (unsigned short*)(ws + TBB) : nullptr;
    float* S = useTB ? (float*)(ws + TBB + ABB) : (float*)ws;
    float* loss_acc    = S + NROIS;                           // S[2048]
    unsigned int* cnt  = (unsigned int*)(S + NROIS + 1);      // S[2049]
    int* lab           = (int*)(S + NROIS + 8);               // S[2056..]

    preprocess<<<useTB ? 4096 : 512, 256, 0, stream>>>(inputs, lut, cq, cand0, cand1,
                                                       tb, ab, lab, S, f, useTB ? 1 : 0);
    if (useTB) main_gemm8<true><<<512, 256, 0, stream>>>(inputs, tb, ab, lut, cq, S);
    else       main_gemm8<false><<<512, 256, 0, stream>>>(inputs, tb, ab, lut, cq, S);
    focal_final<<<512, 256, 0, stream>>>(inputs, lut, lab, S, loss_acc, cnt, f);
}

// Round 9
// 175.298 us; speedup vs baseline: 1.0064x; 1.0064x over previous
//
#include <hip/hip_runtime.h>
#include <hip/hip_bf16.h>

// LOIMLoss on MI355X (gfx950) — R21: 48-class chunks on the PROVEN R14 dist-2
// skeleton (3 rotating buffers, counted vmcnt, wait-then-barrier).
// R20 (64-cls, 2-buffer 2-phase) CRASHED at runtime; audit found no logic bug
// -> suspect the new 2-phase codegen or infra. Retreat to R14's verified
// structure, scaled 32->48 classes: 3 x 24 KB buffers = 72 KB/block (144/CU
// at 2 blocks/CU <= 160). 6 gll16/thread/chunk -> steady vmcnt(6). All
// swizzle/read/source formulas inherit R14's verification (cc&7 == tid>>5).
// Sync ladder so far: 16cls=70.5us, 32cls=62us -> 48cls predicted ~57-60us.
//
// Output model (R11, absmax 0.0): d_out f32[out]; [0]=loss, [1..524289)=inputs
// copy, [524289..)=label bf16-RNE upcast. d_in[0..2] f32.

#define NFEAT 256
#define NROIS 2048
#define NPIDS 5554
#define NCLS 55554            // NPIDS + 50000
#define NCHUNKS 3473          // ceil(NCLS/16)  (non-TB fallback granularity)
#define NCH48 1158            // ceil(NCLS/48)  (TB path granularity)
#define NCLSP (NCH48 * 48)    // 55584: rows [NCLS..NCLSP) zeroed in tb
#define S2F 43.280851226668906f   // 30 * log2(e)
#define LN2F 0.6931471805599453f
#define LOFF 524289

typedef float f32x4 __attribute__((ext_vector_type(4)));
typedef short bf16x8 __attribute__((ext_vector_type(8)));
typedef unsigned short u16x8 __attribute__((ext_vector_type(8)));

#if __has_builtin(__builtin_amdgcn_exp2f)
#define EXP2(x) __builtin_amdgcn_exp2f(x)
#else
#define EXP2(x) exp2f(x)
#endif

__device__ __forceinline__ short bfb(float x) {
    return __builtin_bit_cast(short, __float2bfloat16(x));   // RNE
}

// 16B global->LDS direct (dest = wave-uniform base + lane*16, src per-lane).
__device__ __forceinline__ void gll16(const void* g, void* l) {
    __builtin_amdgcn_global_load_lds(
        (const __attribute__((address_space(1))) void*)g,
        (__attribute__((address_space(3))) void*)l, 16, 0, 0);
}

// ---- kernel A: fused prep + table cvt (+zero pad) + inputs copy + ab cvt ----
__global__ __launch_bounds__(256) void preprocess(
        const float* __restrict__ inputs, const float* __restrict__ lut,
        const float* __restrict__ cq, const int* __restrict__ cand0,
        const int* __restrict__ cand1, unsigned short* __restrict__ tb,
        unsigned short* __restrict__ ab, int* __restrict__ lab,
        float* __restrict__ S, float* __restrict__ f, const int useTB) {
    const int tid = threadIdx.x;
    const int bx = blockIdx.x;

    if (bx == 0) {
        __shared__ int smode;
        __shared__ const int* sT;
        if (tid == 0) {
            const int* T = cand0;
            const unsigned u0 = (unsigned)cand0[0];
            const float f0 = __builtin_bit_cast(float, cand0[0]);
            const bool oki = (u0 >= 1u && u0 <= 6000u);
            const bool okf = (f0 >= 1.0f && f0 <= 6000.0f);
            if (!oki && !okf) T = cand1;
            int mode = 0;                      // 0=int32, 1=int64(LE), 2=f32
            const unsigned tu0 = (unsigned)T[0];
            const float tf0 = __builtin_bit_cast(float, T[0]);
            if (tu0 >= 1u && tu0 <= 6000u) mode = ((T[1] | T[3] | T[5] | T[7]) == 0) ? 1 : 0;
            else if (tf0 >= 1.0f && tf0 <= 6000.0f) mode = 2;
            smode = mode; sT = T;
        }
        __syncthreads();
        const int mode = smode;
        const int* T = sT;
        for (int j = tid; j < NROIS; j += 256) {
            int tv;
            if (mode == 1)      tv = T[2 * j];
            else if (mode == 2) tv = (int)__builtin_bit_cast(float, T[j]);
            else                tv = T[j];
            const int lv = tv - 1;
            lab[j] = lv;
            f[LOFF + j] = __bfloat162float(__float2bfloat16((float)lv));
        }
        for (int j = tid; j < NROIS + 8; j += 256) S[j] = 0.0f;  // S, loss, cnt
    }

    if (bx < 512) {
        const int i = bx * 256 + tid;                 // 131072 float4 units
        const float4 v = *reinterpret_cast<const float4*>(inputs + (size_t)i * 4);
        float* o = f + 1 + (size_t)i * 4;             // f+1 unaligned: scalar stores
        o[0] = v.x; o[1] = v.y; o[2] = v.z; o[3] = v.w;
        if (useTB) {
            ushort4 u;
            u.x = (unsigned short)bfb(v.x); u.y = (unsigned short)bfb(v.y);
            u.z = (unsigned short)bfb(v.z); u.w = (unsigned short)bfb(v.w);
            *reinterpret_cast<ushort4*>(ab + (size_t)i * 4) = u;
        }
    }

    if (useTB) {
        const size_t LUTN = (size_t)NPIDS * NFEAT;    // divisible by 8
        const size_t TOT  = (size_t)NCLS * NFEAT;     // divisible by 8
        const size_t TOTP = (size_t)NCLSP * NFEAT;
        const size_t stride = (size_t)gridDim.x * 256 * 8;
        for (size_t e = ((size_t)bx * 256 + tid) * 8; e < TOTP; e += stride) {
            u16x8 o = {0, 0, 0, 0, 0, 0, 0, 0};
            if (e < TOT) {
                const float* sp = (e < LUTN) ? (lut + e) : (cq + (e - LUTN));
                const float4 a = *reinterpret_cast<const float4*>(sp);
                const float4 b = *reinterpret_cast<const float4*>(sp + 4);
                o[0] = (unsigned short)bfb(a.x); o[1] = (unsigned short)bfb(a.y);
                o[2] = (unsigned short)bfb(a.z); o[3] = (unsigned short)bfb(a.w);
                o[4] = (unsigned short)bfb(b.x); o[5] = (unsigned short)bfb(b.y);
                o[6] = (unsigned short)bfb(b.z); o[7] = (unsigned short)bfb(b.w);
            }
            *reinterpret_cast<u16x8*>(tb + e) = o;
        }
    }
}

// ---- kernel B: main GEMM v10 ------------------------------------------------
// grid 512 = 8 row-groups x 64 class-slices (bx%8 = cs%8 -> XCD-local B slice
// fits 4 MB L2). 4 waves x 64 rows (proven ratio); A resident (128 regs).
// TB path: 48-class chunk (24 KB) staged by 6 gll16/thread into 3 rotating
// LDS buffers; per-chunk sync = "s_waitcnt vmcnt(6); s_barrier" (chunk i+1's
// 6 loads stay in flight across the barrier; only vmem in-loop = gll16 ->
// counts exact). LDS slot (cc,w) = cc*32+w holds global unit w^(4*(cc&7))
// (R14-proven swizzle; staging class cc = (tid>>5)+8k so cc&7 == tid>>5 ->
// single source offset uo). Read slot (h*16+li)*32 + ((q+4kc)^(4*(li&7)))
// returns unit q+4kc. Compute per chunk: 3 sub-chunks x {8 ds_read_b128
// preload -> setprio(1) -> 32 MFMA -> setprio(0) -> 16 exp2-adds}.
template <bool TB>
__global__ __launch_bounds__(256, 2) void main_gemm10(const float* __restrict__ inputs,
                                                      const unsigned short* __restrict__ tb,
                                                      const unsigned short* __restrict__ ab,
                                                      const float* __restrict__ lut,
                                                      const float* __restrict__ cq,
                                                      float* __restrict__ S) {
    __shared__ char lds[73728];                   // 3 x 24 KB (fallback uses 16 KB)
    const int tid = threadIdx.x;
    const int lane = tid & 63;
    const int wave = tid >> 6;
    const int cs = blockIdx.x & 63;
    const int rg = blockIdx.x >> 6;
    const int rowbase = rg * 256 + wave * 64;
    const int li = lane & 15;
    const int q = lane >> 4;
    const int xorli = 4 * (li & 7);
    char* const lbase = &lds[0];

    float sums[4][4] = {{0.f,0.f,0.f,0.f},{0.f,0.f,0.f,0.f},
                        {0.f,0.f,0.f,0.f},{0.f,0.f,0.f,0.f}};

    if constexpr (TB) {
        // A fragments: lane holds A[m=li][k=q*8+kc*32..+7] for 4 row-subtiles
        bf16x8 afrag[4][8];
        #pragma unroll
        for (int s = 0; s < 4; s++) {
            const unsigned short* rp = ab + (size_t)(rowbase + s * 16 + li) * NFEAT + q * 8;
            #pragma unroll
            for (int kc = 0; kc < 8; kc++)
                afrag[s][kc] = *reinterpret_cast<const bf16x8*>(rp + kc * 32);
        }
        // drain afrag loads so gll16 vmcnt counting below is exact
        asm volatile("s_waitcnt vmcnt(0)" ::: "memory");

        // staging: thread owns slots tid+256k (k=0..5); class cc = (tid>>5)+8k;
        // cc&7 == tid>>5 for all k -> one source-swizzle offset uo.
        const int cc0 = tid >> 5;                 // 0..7
        const int uo = ((tid & 31) ^ (4 * cc0)) * 8;
        const int ldd = wave * 1024;              // + k*4096; HW adds lane*16
        const int cA = (cs * NCH48) >> 6;
        const int cB = ((cs + 1) * NCH48) >> 6;
        const int NB = cB - cA;
        const unsigned short* psrc = tb + (size_t)(cA * 48 + cc0) * NFEAT + uo;
        int ob0 = 0, ob1 = 24576, ob2 = 49152;    // rotating buffer byte offsets

        // STAGE one 48-class chunk into the buffer at byte offset ob
        #define STAGE(ob)                                                            \
            {                                                                        \
                _Pragma("unroll")                                                    \
                for (int k = 0; k < 6; k++)                                          \
                    gll16(psrc + (size_t)(8 * k) * NFEAT, lbase + (ob) + ldd + k * 4096); \
                psrc += (size_t)48 * NFEAT;                                          \
            }

        STAGE(ob0);                               // prologue: chunks cA, cA+1
        if (NB > 1) STAGE(ob1);

        for (int i = 0; i < NB; ++i) {
            // wait chunk i landed (chunk i+1's 6 loads stay in flight); wait-
            // THEN-barrier publishes all waves' chunk-i LDS writes; barrier
            // also fences ob2 (last read two iterations ago) before rewrite.
            if (i + 1 < NB) asm volatile("s_waitcnt vmcnt(6)\n\ts_barrier" ::: "memory");
            else            asm volatile("s_waitcnt vmcnt(0)\n\ts_barrier" ::: "memory");
            if (i + 2 < NB) STAGE(ob2);
            #pragma unroll
            for (int h = 0; h < 3; h++) {         // three 16-class sub-chunks
                const int cc = h * 16 + li;
                bf16x8 bfr[8];
                #pragma unroll
                for (int kc = 0; kc < 8; kc++) {
                    const int slot = cc * 32 + ((q + 4 * kc) ^ xorli);
                    bfr[kc] = *reinterpret_cast<const bf16x8*>(lbase + ob0 + slot * 16);
                }
                f32x4 acc[4] = {{0.f,0.f,0.f,0.f},{0.f,0.f,0.f,0.f},
                                {0.f,0.f,0.f,0.f},{0.f,0.f,0.f,0.f}};
                __builtin_amdgcn_s_setprio(1);
                #pragma unroll
                for (int kc = 0; kc < 8; kc++) {
                    acc[0] = __builtin_amdgcn_mfma_f32_16x16x32_bf16(afrag[0][kc], bfr[kc], acc[0], 0, 0, 0);
                    acc[1] = __builtin_amdgcn_mfma_f32_16x16x32_bf16(afrag[1][kc], bfr[kc], acc[1], 0, 0, 0);
                    acc[2] = __builtin_amdgcn_mfma_f32_16x16x32_bf16(afrag[2][kc], bfr[kc], acc[2], 0, 0, 0);
                    acc[3] = __builtin_amdgcn_mfma_f32_16x16x32_bf16(afrag[3][kc], bfr[kc], acc[3], 0, 0, 0);
                }
                __builtin_amdgcn_s_setprio(0);
                // padded tb rows are zero -> exp(-30) ~ 1e-13: no mask needed
                #pragma unroll
                for (int s = 0; s < 4; s++)
                    #pragma unroll
                    for (int r = 0; r < 4; r++)
                        sums[s][r] += EXP2(S2F * acc[s][r] - S2F);
            }
            const int t = ob0; ob0 = ob1; ob1 = ob2; ob2 = t;
        }
        #undef STAGE
    } else {
        // fallback (no ws table): R14 reg-staged double-buffer loop (proven).
        bf16x8 afrag[4][8];
        #pragma unroll
        for (int s = 0; s < 4; s++) {
            const float* rp = inputs + (size_t)(rowbase + s * 16 + li) * NFEAT + q * 8;
            #pragma unroll
            for (int kc = 0; kc < 8; kc++) {
                const float4 x0 = *reinterpret_cast<const float4*>(rp + kc * 32);
                const float4 x1 = *reinterpret_cast<const float4*>(rp + kc * 32 + 4);
                bf16x8 a;
                a[0] = bfb(x0.x); a[1] = bfb(x0.y); a[2] = bfb(x0.z); a[3] = bfb(x0.w);
                a[4] = bfb(x1.x); a[5] = bfb(x1.y); a[6] = bfb(x1.z); a[7] = bfb(x1.w);
                afrag[s][kc] = a;
            }
        }
        short* fb = (short*)lbase;
        const int s0 = tid, s1 = tid + 256;
        const int cc0 = s0 >> 5, cc1 = s1 >> 5;
        const int uo0 = ((s0 & 31) ^ (4 * (cc0 & 7))) * 8;
        const int uo1 = ((s1 & 31) ^ (4 * (cc1 & 7))) * 8;
        const int cA = (cs * NCHUNKS) >> 6;
        const int cB = ((cs + 1) * NCHUNKS) >> 6;
        {
            int n0 = cA * 16 + cc0; n0 = n0 < (NCLS - 1) ? n0 : (NCLS - 1);
            int n1 = cA * 16 + cc1; n1 = n1 < (NCLS - 1) ? n1 : (NCLS - 1);
            const float* r0 = ((n0 < NPIDS) ? lut + (size_t)n0 * NFEAT
                                            : cq + (size_t)(n0 - NPIDS) * NFEAT) + uo0;
            const float* r1 = ((n1 < NPIDS) ? lut + (size_t)n1 * NFEAT
                                            : cq + (size_t)(n1 - NPIDS) * NFEAT) + uo1;
            const float4 a0 = *reinterpret_cast<const float4*>(r0);
            const float4 a1 = *reinterpret_cast<const float4*>(r0 + 4);
            const float4 b0 = *reinterpret_cast<const float4*>(r1);
            const float4 b1 = *reinterpret_cast<const float4*>(r1 + 4);
            bf16x8 v0, v1;
            v0[0]=bfb(a0.x); v0[1]=bfb(a0.y); v0[2]=bfb(a0.z); v0[3]=bfb(a0.w);
            v0[4]=bfb(a1.x); v0[5]=bfb(a1.y); v0[6]=bfb(a1.z); v0[7]=bfb(a1.w);
            v1[0]=bfb(b0.x); v1[1]=bfb(b0.y); v1[2]=bfb(b0.z); v1[3]=bfb(b0.w);
            v1[4]=bfb(b1.x); v1[5]=bfb(b1.y); v1[6]=bfb(b1.z); v1[7]=bfb(b1.w);
            *reinterpret_cast<bf16x8*>(&fb[s0 * 8]) = v0;
            *reinterpret_cast<bf16x8*>(&fb[s1 * 8]) = v1;
        }
        __syncthreads();
        int cur = 0;
        for (int ci = cA; ci < cB; ++ci) {
            const bool pf = (ci + 1 < cB);
            float4 f0a, f0b, f1a, f1b;
            if (pf) {
                int n0 = (ci + 1) * 16 + cc0; n0 = n0 < (NCLS - 1) ? n0 : (NCLS - 1);
                int n1 = (ci + 1) * 16 + cc1; n1 = n1 < (NCLS - 1) ? n1 : (NCLS - 1);
                const float* r0 = ((n0 < NPIDS) ? lut + (size_t)n0 * NFEAT
                                                : cq + (size_t)(n0 - NPIDS) * NFEAT) + uo0;
                const float* r1 = ((n1 < NPIDS) ? lut + (size_t)n1 * NFEAT
                                                : cq + (size_t)(n1 - NPIDS) * NFEAT) + uo1;
                f0a = *reinterpret_cast<const float4*>(r0);
                f0b = *reinterpret_cast<const float4*>(r0 + 4);
                f1a = *reinterpret_cast<const float4*>(r1);
                f1b = *reinterpret_cast<const float4*>(r1 + 4);
            }
            f32x4 acc[4] = {{0.f,0.f,0.f,0.f},{0.f,0.f,0.f,0.f},
                            {0.f,0.f,0.f,0.f},{0.f,0.f,0.f,0.f}};
            #pragma unroll
            for (int kc = 0; kc < 8; kc++) {
                const int slot = li * 32 + ((q + 4 * kc) ^ xorli);
                const bf16x8 b = *reinterpret_cast<const bf16x8*>(&fb[cur * 4096 + slot * 8]);
                acc[0] = __builtin_amdgcn_mfma_f32_16x16x32_bf16(afrag[0][kc], b, acc[0], 0, 0, 0);
                acc[1] = __builtin_amdgcn_mfma_f32_16x16x32_bf16(afrag[1][kc], b, acc[1], 0, 0, 0);
                acc[2] = __builtin_amdgcn_mfma_f32_16x16x32_bf16(afrag[2][kc], b, acc[2], 0, 0, 0);
                acc[3] = __builtin_amdgcn_mfma_f32_16x16x32_bf16(afrag[3][kc], b, acc[3], 0, 0, 0);
            }
            const float valid = ((ci * 16 + li) < NCLS) ? 1.0f : 0.0f;
            #pragma unroll
            for (int s = 0; s < 4; s++)
                #pragma unroll
                for (int r = 0; r < 4; r++)
                    sums[s][r] += valid * EXP2(S2F * (acc[s][r] - 1.0f));
            if (pf) {
                bf16x8 p0, p1;
                p0[0]=bfb(f0a.x); p0[1]=bfb(f0a.y); p0[2]=bfb(f0a.z); p0[3]=bfb(f0a.w);
                p0[4]=bfb(f0b.x); p0[5]=bfb(f0b.y); p0[6]=bfb(f0b.z); p0[7]=bfb(f0b.w);
                p1[0]=bfb(f1a.x); p1[1]=bfb(f1a.y); p1[2]=bfb(f1a.z); p1[3]=bfb(f1a.w);
                p1[4]=bfb(f1b.x); p1[5]=bfb(f1b.y); p1[6]=bfb(f1b.z); p1[7]=bfb(f1b.w);
                *reinterpret_cast<bf16x8*>(&fb[(cur ^ 1) * 4096 + s0 * 8]) = p0;
                *reinterpret_cast<bf16x8*>(&fb[(cur ^ 1) * 4096 + s1 * 8]) = p1;
            }
            __syncthreads();
            cur ^= 1;
        }
    }

    // reduce over the 16 class-lanes, atomically add per-row sum-exp
    #pragma unroll
    for (int s = 0; s < 4; s++)
        #pragma unroll
        for (int r = 0; r < 4; r++) {
            float v = sums[s][r];
            v += __shfl_xor(v, 1); v += __shfl_xor(v, 2);
            v += __shfl_xor(v, 4); v += __shfl_xor(v, 8);
            sums[s][r] = v;
        }
    if (li == 0) {
        #pragma unroll
        for (int s = 0; s < 4; s++)
            #pragma unroll
            for (int r = 0; r < 4; r++)
                atomicAdd(&S[rowbase + s * 16 + q * 4 + r], sums[s][r]);
    }
}

// ---- kernel C: exact f32 label dot + focal; last block writes loss ---------
__global__ __launch_bounds__(256) void focal_final(const float* __restrict__ inputs,
                                                   const float* __restrict__ lut,
                                                   const int* __restrict__ lab,
                                                   const float* __restrict__ S,
                                                   float* __restrict__ loss_acc,
                                                   unsigned int* __restrict__ cnt,
                                                   float* __restrict__ f) {
    const int wave = threadIdx.x >> 6;
    const int lane = threadIdx.x & 63;
    const int row = blockIdx.x * 4 + wave;
    const int label = lab[row];
    const bool valid = (label >= 0 && label < NPIDS);
    const int lr = valid ? label : 0;
    const float4 a = *reinterpret_cast<const float4*>(inputs + (size_t)row * NFEAT + lane * 4);
    const float4 b = *reinterpret_cast<const float4*>(lut + (size_t)lr * NFEAT + lane * 4);
    float v = a.x * b.x + a.y * b.y + a.z * b.z + a.w * b.w;
    #pragma unroll
    for (int m = 1; m < 64; m <<= 1) v += __shfl_xor(v, m);

    __shared__ float red[4];
    if (lane == 0) {
        float fo = 0.0f;
        if (valid) {
            const float l2 = v * S2F;
            const float lse2 = S2F + log2f(S[row]);
            float ce = fmaxf((lse2 - l2) * LN2F, 0.0f);
            const float pt = EXP2(l2 - lse2);
            const float om = 1.0f - pt;
            fo = om * om * ce;
        }
        red[wave] = fo;
    }
    __syncthreads();
    if (threadIdx.x == 0) {
        atomicAdd(loss_acc, red[0] + red[1] + red[2] + red[3]);
        __threadfence();
        const unsigned done = atomicAdd(cnt, 1u) + 1u;
        if (done == gridDim.x) {                       // last block: write loss
            const float tot = atomicAdd(loss_acc, 0.0f);  // coherent read
            f[0] = tot * (1.0f / NROIS);
        }
    }
}

extern "C" void kernel_launch(void* const* d_in, const int* in_sizes, int n_in,
                              void* d_out, int out_size, void* d_ws, size_t ws_size,
                              hipStream_t stream) {
    const float* inputs = (const float*)d_in[0];
    const float* lut    = (const float*)d_in[1];
    const float* cq     = (const float*)d_in[2];
    const int*   cand0  = (const int*)d_in[3];     // targets
    const int*   cand1  = (const int*)((n_in > 4) ? d_in[4] : d_in[3]);
    float* f = (float*)d_out;

    const size_t TBB = (size_t)NCLSP * NFEAT * 2;  // 28.46 MB padded bf16 table
    const size_t ABB = (size_t)NROIS * NFEAT * 2;  // 1 MB bf16 A
    char* ws = (char*)d_ws;
    const bool useTB = ws_size >= TBB + ABB + 32768;

    unsigned short* tb = useTB ? (unsigned short*)ws : nullptr;
    unsigned short* ab = useTB ? (unsigned short*)(ws + TBB) : nullptr;
    float* S = useTB ? (float*)(ws + TBB + ABB) : (float*)ws;
    float* loss_acc    = S + NROIS;                           // S[2048]
    unsigned int* cnt  = (unsigned int*)(S + NROIS + 1);      // S[2049]
    int* lab           = (int*)(S + NROIS + 8);               // S[2056..]

    preprocess<<<useTB ? 4096 : 512, 256, 0, stream>>>(inputs, lut, cq, cand0, cand1,
                                                       tb, ab, lab, S, f, useTB ? 1 : 0);
    if (useTB) main_gemm10<true><<<512, 256, 0, stream>>>(inputs, tb, ab, lut, cq, S);
    else       main_gemm10<false><<<512, 256, 0, stream>>>(inputs, tb, ab, lut, cq, S);
    focal_final<<<512, 256, 0, stream>>>(inputs, lut, lab, S, loss_acc, cnt, f);
}

// Round 10
// 170.712 us; speedup vs baseline: 1.0334x; 1.0269x over previous
//
#include <hip/hip_runtime.h>
#include <hip/hip_bf16.h>

// LOIMLoss on MI355X (gfx950) — R22: consolidation. EXACT revert to R14, the
// measured-best kernel (gemm 61.7-62.6us, total 172.4us).
// Sync-granularity ladder (proven): 16cls=70.5, 32cls=62 (MIN), 48cls=66,
// 64cls=crash. Structural probes that FAILED around the 62us floor: 32x32
// MFMA (82us, swizzle conflicts), 8-wave occupancy (79us, LDS-BW-bound),
// coop mega-fusion (220us), deferred-exp (neutral), barrier-free streams
// (70us), 48-cls (66us). Budget: ~97us fixed harness overhead + ~14us
// BW-bound preprocess + 62us gemm = measured total. Gemm = 940 TF = 37.6% of
// dense peak (MfmaUtil 37 / VALUBusy 30) — the documented 2-barrier-structure
// ceiling; 8-phase-style grafts regressed (consistent with m196). fp8/MX
// rejected: risks the absmax-0.0 exactness contract.
//
// Output model (R11, absmax 0.0): d_out f32[out]; [0]=loss, [1..524289)=inputs
// copy, [524289..)=label bf16-RNE upcast. d_in[0..2] f32.

#define NFEAT 256
#define NROIS 2048
#define NPIDS 5554
#define NCLS 55554            // NPIDS + 50000
#define NCHUNKS 3473          // ceil(NCLS/16)  (non-TB fallback granularity)
#define NCH32 1737            // ceil(NCLS/32)  (TB path granularity)
#define NCLSP (NCH32 * 32)    // 55584: rows [NCLS..NCLSP) zeroed in tb
#define S2F 43.280851226668906f   // 30 * log2(e)
#define LN2F 0.6931471805599453f
#define LOFF 524289

typedef float f32x4 __attribute__((ext_vector_type(4)));
typedef short bf16x8 __attribute__((ext_vector_type(8)));
typedef unsigned short u16x8 __attribute__((ext_vector_type(8)));

#if __has_builtin(__builtin_amdgcn_exp2f)
#define EXP2(x) __builtin_amdgcn_exp2f(x)
#else
#define EXP2(x) exp2f(x)
#endif

__device__ __forceinline__ short bfb(float x) {
    return __builtin_bit_cast(short, __float2bfloat16(x));   // RNE
}

// 16B global->LDS direct (dest = wave-uniform base + lane*16, src per-lane).
__device__ __forceinline__ void gll16(const void* g, void* l) {
    __builtin_amdgcn_global_load_lds(
        (const __attribute__((address_space(1))) void*)g,
        (__attribute__((address_space(3))) void*)l, 16, 0, 0);
}

// ---- kernel A: fused prep + table cvt (+zero pad) + inputs copy + ab cvt ----
__global__ __launch_bounds__(256) void preprocess(
        const float* __restrict__ inputs, const float* __restrict__ lut,
        const float* __restrict__ cq, const int* __restrict__ cand0,
        const int* __restrict__ cand1, unsigned short* __restrict__ tb,
        unsigned short* __restrict__ ab, int* __restrict__ lab,
        float* __restrict__ S, float* __restrict__ f, const int useTB) {
    const int tid = threadIdx.x;
    const int bx = blockIdx.x;

    if (bx == 0) {
        __shared__ int smode;
        __shared__ const int* sT;
        if (tid == 0) {
            const int* T = cand0;
            const unsigned u0 = (unsigned)cand0[0];
            const float f0 = __builtin_bit_cast(float, cand0[0]);
            const bool oki = (u0 >= 1u && u0 <= 6000u);
            const bool okf = (f0 >= 1.0f && f0 <= 6000.0f);
            if (!oki && !okf) T = cand1;
            int mode = 0;                      // 0=int32, 1=int64(LE), 2=f32
            const unsigned tu0 = (unsigned)T[0];
            const float tf0 = __builtin_bit_cast(float, T[0]);
            if (tu0 >= 1u && tu0 <= 6000u) mode = ((T[1] | T[3] | T[5] | T[7]) == 0) ? 1 : 0;
            else if (tf0 >= 1.0f && tf0 <= 6000.0f) mode = 2;
            smode = mode; sT = T;
        }
        __syncthreads();
        const int mode = smode;
        const int* T = sT;
        for (int j = tid; j < NROIS; j += 256) {
            int tv;
            if (mode == 1)      tv = T[2 * j];
            else if (mode == 2) tv = (int)__builtin_bit_cast(float, T[j]);
            else                tv = T[j];
            const int lv = tv - 1;
            lab[j] = lv;
            f[LOFF + j] = __bfloat162float(__float2bfloat16((float)lv));
        }
        for (int j = tid; j < NROIS + 8; j += 256) S[j] = 0.0f;  // S, loss, cnt
    }

    if (bx < 512) {
        const int i = bx * 256 + tid;                 // 131072 float4 units
        const float4 v = *reinterpret_cast<const float4*>(inputs + (size_t)i * 4);
        float* o = f + 1 + (size_t)i * 4;             // f+1 unaligned: scalar stores
        o[0] = v.x; o[1] = v.y; o[2] = v.z; o[3] = v.w;
        if (useTB) {
            ushort4 u;
            u.x = (unsigned short)bfb(v.x); u.y = (unsigned short)bfb(v.y);
            u.z = (unsigned short)bfb(v.z); u.w = (unsigned short)bfb(v.w);
            *reinterpret_cast<ushort4*>(ab + (size_t)i * 4) = u;
        }
    }

    if (useTB) {
        const size_t LUTN = (size_t)NPIDS * NFEAT;    // divisible by 8
        const size_t TOT  = (size_t)NCLS * NFEAT;     // divisible by 8
        const size_t TOTP = (size_t)NCLSP * NFEAT;
        const size_t stride = (size_t)gridDim.x * 256 * 8;
        for (size_t e = ((size_t)bx * 256 + tid) * 8; e < TOTP; e += stride) {
            u16x8 o = {0, 0, 0, 0, 0, 0, 0, 0};
            if (e < TOT) {
                const float* sp = (e < LUTN) ? (lut + e) : (cq + (e - LUTN));
                const float4 a = *reinterpret_cast<const float4*>(sp);
                const float4 b = *reinterpret_cast<const float4*>(sp + 4);
                o[0] = (unsigned short)bfb(a.x); o[1] = (unsigned short)bfb(a.y);
                o[2] = (unsigned short)bfb(a.z); o[3] = (unsigned short)bfb(a.w);
                o[4] = (unsigned short)bfb(b.x); o[5] = (unsigned short)bfb(b.y);
                o[6] = (unsigned short)bfb(b.z); o[7] = (unsigned short)bfb(b.w);
            }
            *reinterpret_cast<u16x8*>(tb + e) = o;
        }
    }
}

// ---- kernel B: main GEMM (R14, measured 62us) -------------------------------
// grid 512 = 8 row-groups x 64 class-slices (bx%8 = cs%8 -> XCD-local B slice
// ~3.56 MB fits 4 MB L2). 4 waves x 64 rows; A resident bf16 frags (128 regs).
// TB path: 32-class chunk (16 KB) staged by 4 gll16/thread into 3 rotating
// LDS buffers; per-chunk sync = "s_waitcnt vmcnt(4); s_barrier" (next chunk's
// 4 loads stay in flight across the barrier; only vmem in-loop = gll16 ->
// counts exact). LDS slot cc*32+p holds global unit p^(4*(cc&7)); read slot
// cc*32+((q+4kc)^(4*(li&7))) returns unit q+4kc (conflict cost ~4cyc/read).
// Compute per chunk: 2 sub-chunks x {8 ds_read_b128 preload -> setprio(1) ->
// 32 MFMA -> setprio(0) -> 16 exp2-adds}.
template <bool TB>
__global__ __launch_bounds__(256, 2) void main_gemm4(const float* __restrict__ inputs,
                                                     const unsigned short* __restrict__ tb,
                                                     const unsigned short* __restrict__ ab,
                                                     const float* __restrict__ lut,
                                                     const float* __restrict__ cq,
                                                     float* __restrict__ S) {
    __shared__ short ldsb[3][8192];               // 3 x 16 KB (fallback uses 2x8KB)
    const int tid = threadIdx.x;
    const int lane = tid & 63;
    const int wave = tid >> 6;
    const int cs = blockIdx.x & 63;
    const int rg = blockIdx.x >> 6;
    const int rowbase = rg * 256 + wave * 64;
    const int li = lane & 15;
    const int q = lane >> 4;
    const int xorli = 4 * (li & 7);

    bf16x8 afrag[4][8];
    if constexpr (TB) {
        #pragma unroll
        for (int s = 0; s < 4; s++) {
            const unsigned short* rp = ab + (size_t)(rowbase + s * 16 + li) * NFEAT + q * 8;
            #pragma unroll
            for (int kc = 0; kc < 8; kc++)
                afrag[s][kc] = *reinterpret_cast<const bf16x8*>(rp + kc * 32);
        }
    } else {
        #pragma unroll
        for (int s = 0; s < 4; s++) {
            const float* rp = inputs + (size_t)(rowbase + s * 16 + li) * NFEAT + q * 8;
            #pragma unroll
            for (int kc = 0; kc < 8; kc++) {
                const float4 x0 = *reinterpret_cast<const float4*>(rp + kc * 32);
                const float4 x1 = *reinterpret_cast<const float4*>(rp + kc * 32 + 4);
                bf16x8 a;
                a[0] = bfb(x0.x); a[1] = bfb(x0.y); a[2] = bfb(x0.z); a[3] = bfb(x0.w);
                a[4] = bfb(x1.x); a[5] = bfb(x1.y); a[6] = bfb(x1.z); a[7] = bfb(x1.w);
                afrag[s][kc] = a;
            }
        }
    }

    float sums[4][4] = {{0.f,0.f,0.f,0.f},{0.f,0.f,0.f,0.f},
                        {0.f,0.f,0.f,0.f},{0.f,0.f,0.f,0.f}};
    char* const lbase = (char*)&ldsb[0][0];

    if constexpr (TB) {
        const int cc0 = tid >> 5;
        const int uo = ((tid & 31) ^ (4 * (cc0 & 7))) * 8;
        const int ldd = wave * 1024;             // + k*4096, HW adds lane*16
        const int cA = (cs * NCH32) >> 6;
        const int cB = ((cs + 1) * NCH32) >> 6;
        const int NB = cB - cA;
        const unsigned short* psrc = tb + (size_t)(cA * 32 + cc0) * NFEAT + uo;
        int ob0 = 0, ob1 = 16384, ob2 = 32768;

        #pragma unroll
        for (int k = 0; k < 4; k++)
            gll16(psrc + (size_t)(8 * k) * NFEAT, lbase + ob0 + ldd + k * 4096);
        psrc += (size_t)32 * NFEAT;
        if (NB > 1) {
            #pragma unroll
            for (int k = 0; k < 4; k++)
                gll16(psrc + (size_t)(8 * k) * NFEAT, lbase + ob1 + ldd + k * 4096);
            psrc += (size_t)32 * NFEAT;
        }

        for (int i = 0; i < NB; ++i) {
            if (i + 1 < NB) asm volatile("s_waitcnt vmcnt(4)\n\ts_barrier" ::: "memory");
            else            asm volatile("s_waitcnt vmcnt(0)\n\ts_barrier" ::: "memory");
            if (i + 2 < NB) {
                #pragma unroll
                for (int k = 0; k < 4; k++)
                    gll16(psrc + (size_t)(8 * k) * NFEAT, lbase + ob2 + ldd + k * 4096);
                psrc += (size_t)32 * NFEAT;
            }
            #pragma unroll
            for (int h = 0; h < 2; h++) {        // two 16-class sub-chunks
                const int cc = h * 16 + li;
                bf16x8 bfr[8];
                #pragma unroll
                for (int kc = 0; kc < 8; kc++) {
                    const int slot = cc * 32 + ((q + 4 * kc) ^ xorli);
                    bfr[kc] = *reinterpret_cast<const bf16x8*>(lbase + ob0 + slot * 16);
                }
                f32x4 acc[4] = {{0.f,0.f,0.f,0.f},{0.f,0.f,0.f,0.f},
                                {0.f,0.f,0.f,0.f},{0.f,0.f,0.f,0.f}};
                __builtin_amdgcn_s_setprio(1);
                #pragma unroll
                for (int kc = 0; kc < 8; kc++) {
                    acc[0] = __builtin_amdgcn_mfma_f32_16x16x32_bf16(afrag[0][kc], bfr[kc], acc[0], 0, 0, 0);
                    acc[1] = __builtin_amdgcn_mfma_f32_16x16x32_bf16(afrag[1][kc], bfr[kc], acc[1], 0, 0, 0);
                    acc[2] = __builtin_amdgcn_mfma_f32_16x16x32_bf16(afrag[2][kc], bfr[kc], acc[2], 0, 0, 0);
                    acc[3] = __builtin_amdgcn_mfma_f32_16x16x32_bf16(afrag[3][kc], bfr[kc], acc[3], 0, 0, 0);
                }
                __builtin_amdgcn_s_setprio(0);
                // padded tb rows are zero -> exp(-30) ~ 1e-13: no mask needed
                #pragma unroll
                for (int s = 0; s < 4; s++)
                    #pragma unroll
                    for (int r = 0; r < 4; r++)
                        sums[s][r] += EXP2(S2F * acc[s][r] - S2F);
            }
            const int t = ob0; ob0 = ob1; ob1 = ob2; ob2 = t;
        }
    } else {
        short* fb = (short*)lbase;
        const int s0 = tid, s1 = tid + 256;
        const int cc0 = s0 >> 5, cc1 = s1 >> 5;
        const int uo0 = ((s0 & 31) ^ (4 * (cc0 & 7))) * 8;
        const int uo1 = ((s1 & 31) ^ (4 * (cc1 & 7))) * 8;
        const int cA = (cs * NCHUNKS) >> 6;
        const int cB = ((cs + 1) * NCHUNKS) >> 6;
        {
            int n0 = cA * 16 + cc0; n0 = n0 < (NCLS - 1) ? n0 : (NCLS - 1);
            int n1 = cA * 16 + cc1; n1 = n1 < (NCLS - 1) ? n1 : (NCLS - 1);
            const float* r0 = ((n0 < NPIDS) ? lut + (size_t)n0 * NFEAT
                                            : cq + (size_t)(n0 - NPIDS) * NFEAT) + uo0;
            const float* r1 = ((n1 < NPIDS) ? lut + (size_t)n1 * NFEAT
                                            : cq + (size_t)(n1 - NPIDS) * NFEAT) + uo1;
            const float4 a0 = *reinterpret_cast<const float4*>(r0);
            const float4 a1 = *reinterpret_cast<const float4*>(r0 + 4);
            const float4 b0 = *reinterpret_cast<const float4*>(r1);
            const float4 b1 = *reinterpret_cast<const float4*>(r1 + 4);
            bf16x8 v0, v1;
            v0[0]=bfb(a0.x); v0[1]=bfb(a0.y); v0[2]=bfb(a0.z); v0[3]=bfb(a0.w);
            v0[4]=bfb(a1.x); v0[5]=bfb(a1.y); v0[6]=bfb(a1.z); v0[7]=bfb(a1.w);
            v1[0]=bfb(b0.x); v1[1]=bfb(b0.y); v1[2]=bfb(b0.z); v1[3]=bfb(b0.w);
            v1[4]=bfb(b1.x); v1[5]=bfb(b1.y); v1[6]=bfb(b1.z); v1[7]=bfb(b1.w);
            *reinterpret_cast<bf16x8*>(&fb[s0 * 8]) = v0;
            *reinterpret_cast<bf16x8*>(&fb[s1 * 8]) = v1;
        }
        __syncthreads();
        int cur = 0;
        for (int ci = cA; ci < cB; ++ci) {
            const bool pf = (ci + 1 < cB);
            float4 f0a, f0b, f1a, f1b;
            if (pf) {
                int n0 = (ci + 1) * 16 + cc0; n0 = n0 < (NCLS - 1) ? n0 : (NCLS - 1);
                int n1 = (ci + 1) * 16 + cc1; n1 = n1 < (NCLS - 1) ? n1 : (NCLS - 1);
                const float* r0 = ((n0 < NPIDS) ? lut + (size_t)n0 * NFEAT
                                                : cq + (size_t)(n0 - NPIDS) * NFEAT) + uo0;
                const float* r1 = ((n1 < NPIDS) ? lut + (size_t)n1 * NFEAT
                                                : cq + (size_t)(n1 - NPIDS) * NFEAT) + uo1;
                f0a = *reinterpret_cast<const float4*>(r0);
                f0b = *reinterpret_cast<const float4*>(r0 + 4);
                f1a = *reinterpret_cast<const float4*>(r1);
                f1b = *reinterpret_cast<const float4*>(r1 + 4);
            }
            f32x4 acc[4] = {{0.f,0.f,0.f,0.f},{0.f,0.f,0.f,0.f},
                            {0.f,0.f,0.f,0.f},{0.f,0.f,0.f,0.f}};
            #pragma unroll
            for (int kc = 0; kc < 8; kc++) {
                const int slot = li * 32 + ((q + 4 * kc) ^ xorli);
                const bf16x8 b = *reinterpret_cast<const bf16x8*>(&fb[cur * 4096 + slot * 8]);
                acc[0] = __builtin_amdgcn_mfma_f32_16x16x32_bf16(afrag[0][kc], b, acc[0], 0, 0, 0);
                acc[1] = __builtin_amdgcn_mfma_f32_16x16x32_bf16(afrag[1][kc], b, acc[1], 0, 0, 0);
                acc[2] = __builtin_amdgcn_mfma_f32_16x16x32_bf16(afrag[2][kc], b, acc[2], 0, 0, 0);
                acc[3] = __builtin_amdgcn_mfma_f32_16x16x32_bf16(afrag[3][kc], b, acc[3], 0, 0, 0);
            }
            const float valid = ((ci * 16 + li) < NCLS) ? 1.0f : 0.0f;
            #pragma unroll
            for (int s = 0; s < 4; s++)
                #pragma unroll
                for (int r = 0; r < 4; r++)
                    sums[s][r] += valid * EXP2(S2F * (acc[s][r] - 1.0f));
            if (pf) {
                bf16x8 p0, p1;
                p0[0]=bfb(f0a.x); p0[1]=bfb(f0a.y); p0[2]=bfb(f0a.z); p0[3]=bfb(f0a.w);
                p0[4]=bfb(f0b.x); p0[5]=bfb(f0b.y); p0[6]=bfb(f0b.z); p0[7]=bfb(f0b.w);
                p1[0]=bfb(f1a.x); p1[1]=bfb(f1a.y); p1[2]=bfb(f1a.z); p1[3]=bfb(f1a.w);
                p1[4]=bfb(f1b.x); p1[5]=bfb(f1b.y); p1[6]=bfb(f1b.z); p1[7]=bfb(f1b.w);
                *reinterpret_cast<bf16x8*>(&fb[(cur ^ 1) * 4096 + s0 * 8]) = p0;
                *reinterpret_cast<bf16x8*>(&fb[(cur ^ 1) * 4096 + s1 * 8]) = p1;
            }
            __syncthreads();
            cur ^= 1;
        }
    }

    // reduce over the 16 class-lanes, atomically add per-row sum-exp
    #pragma unroll
    for (int s = 0; s < 4; s++)
        #pragma unroll
        for (int r = 0; r < 4; r++) {
            float v = sums[s][r];
            v += __shfl_xor(v, 1); v += __shfl_xor(v, 2);
            v += __shfl_xor(v, 4); v += __shfl_xor(v, 8);
            sums[s][r] = v;
        }
    if (li == 0) {
        #pragma unroll
        for (int s = 0; s < 4; s++)
            #pragma unroll
            for (int r = 0; r < 4; r++)
                atomicAdd(&S[rowbase + s * 16 + q * 4 + r], sums[s][r]);
    }
}

// ---- kernel C: exact f32 label dot + focal; last block writes loss ---------
__global__ __launch_bounds__(256) void focal_final(const float* __restrict__ inputs,
                                                   const float* __restrict__ lut,
                                                   const int* __restrict__ lab,
                                                   const float* __restrict__ S,
                                                   float* __restrict__ loss_acc,
                                                   unsigned int* __restrict__ cnt,
                                                   float* __restrict__ f) {
    const int wave = threadIdx.x >> 6;
    const int lane = threadIdx.x & 63;
    const int row = blockIdx.x * 4 + wave;
    const int label = lab[row];
    const bool valid = (label >= 0 && label < NPIDS);
    const int lr = valid ? label : 0;
    const float4 a = *reinterpret_cast<const float4*>(inputs + (size_t)row * NFEAT + lane * 4);
    const float4 b = *reinterpret_cast<const float4*>(lut + (size_t)lr * NFEAT + lane * 4);
    float v = a.x * b.x + a.y * b.y + a.z * b.z + a.w * b.w;
    #pragma unroll
    for (int m = 1; m < 64; m <<= 1) v += __shfl_xor(v, m);

    __shared__ float red[4];
    if (lane == 0) {
        float fo = 0.0f;
        if (valid) {
            const float l2 = v * S2F;
            const float lse2 = S2F + log2f(S[row]);
            float ce = fmaxf((lse2 - l2) * LN2F, 0.0f);
            const float pt = EXP2(l2 - lse2);
            const float om = 1.0f - pt;
            fo = om * om * ce;
        }
        red[wave] = fo;
    }
    __syncthreads();
    if (threadIdx.x == 0) {
        atomicAdd(loss_acc, red[0] + red[1] + red[2] + red[3]);
        __threadfence();
        const unsigned done = atomicAdd(cnt, 1u) + 1u;
        if (done == gridDim.x) {                       // last block: write loss
            const float tot = atomicAdd(loss_acc, 0.0f);  // coherent read
            f[0] = tot * (1.0f / NROIS);
        }
    }
}

extern "C" void kernel_launch(void* const* d_in, const int* in_sizes, int n_in,
                              void* d_out, int out_size, void* d_ws, size_t ws_size,
                              hipStream_t stream) {
    const float* inputs = (const float*)d_in[0];
    const float* lut    = (const float*)d_in[1];
    const float* cq     = (const float*)d_in[2];
    const int*   cand0  = (const int*)d_in[3];     // targets
    const int*   cand1  = (const int*)((n_in > 4) ? d_in[4] : d_in[3]);
    float* f = (float*)d_out;

    const size_t TBB = (size_t)NCLSP * NFEAT * 2;  // 28.46 MB padded bf16 table
    const size_t ABB = (size_t)NROIS * NFEAT * 2;  // 1 MB bf16 A
    char* ws = (char*)d_ws;
    const bool useTB = ws_size >= TBB + ABB + 32768;

    unsigned short* tb = useTB ? (unsigned short*)ws : nullptr;
    unsigned short* ab = useTB ? (unsigned short*)(ws + TBB) : nullptr;
    float* S = useTB ? (float*)(ws + TBB + ABB) : (float*)ws;
    float* loss_acc    = S + NROIS;                           // S[2048]
    unsigned int* cnt  = (unsigned int*)(S + NROIS + 1);      // S[2049]
    int* lab           = (int*)(S + NROIS + 8);               // S[2056..]

    preprocess<<<useTB ? 4096 : 512, 256, 0, stream>>>(inputs, lut, cq, cand0, cand1,
                                                       tb, ab, lab, S, f, useTB ? 1 : 0);
    if (useTB) main_gemm4<true><<<512, 256, 0, stream>>>(inputs, tb, ab, lut, cq, S);
    else       main_gemm4<false><<<512, 256, 0, stream>>>(inputs, tb, ab, lut, cq, S);
    focal_final<<<512, 256, 0, stream>>>(inputs, lut, lab, S, loss_acc, cnt, f);
}